// Round 3
// baseline (37.601 us; speedup 1.0000x reference)
//
#include <hip/hip_runtime.h>
#include <hip/hip_bf16.h>
#include <math.h>

#define BB 8
#define SS 2048
#define HH 768
#define NN 512
#define MAXW 30

#define GEMV_BLOCKS (BB * SS / 4)   // wave per token, 4 waves/block -> 4096 blocks

// ---- Prep: token-score GEMV (blocks < gemv_blocks) + per-example counting
//      sort (last BB blocks). Sort hides under the GEMV.
__global__ __launch_bounds__(256) void prep_kernel(
    const float* __restrict__ emb,      // (B, S, H)
    const float* __restrict__ w,        // (H)
    const float* __restrict__ bias,     // (1)
    const int*   __restrict__ starts,   // (B, N)
    float*       __restrict__ scores,   // (B*S) or unused
    int*         __restrict__ order,    // (B*N) or unused
    int gemv_blocks)
{
    const int tid = threadIdx.x;
    if ((int)blockIdx.x < gemv_blocks) {
        const int wv = tid >> 6, lane = tid & 63;
        const int token = blockIdx.x * 4 + wv;          // 0 .. B*S-1
        const float* row = emb + (size_t)token * HH;
        const int h0 = lane * 4;
        float acc = 0.f;
        #pragma unroll
        for (int k = 0; k < 3; ++k) {
            float4 e4 = *reinterpret_cast<const float4*>(row + h0 + k * 256);
            float4 w4 = *reinterpret_cast<const float4*>(w + h0 + k * 256);
            acc += e4.x * w4.x + e4.y * w4.y + e4.z * w4.z + e4.w * w4.w;
        }
        #pragma unroll
        for (int off = 32; off; off >>= 1) acc += __shfl_xor(acc, off);
        if (lane == 0) scores[token] = acc + bias[0];
    } else {
        const int b = blockIdx.x - gemv_blocks;
        __shared__ int hist[SS];
        __shared__ int partial[256];
        for (int i = tid; i < SS; i += 256) hist[i] = 0;
        __syncthreads();
        const int* st = starts + b * NN;
        for (int n = tid; n < NN; n += 256) atomicAdd(&hist[st[n]], 1);
        __syncthreads();
        const int base = tid * 8;
        int s = 0;
        #pragma unroll
        for (int k = 0; k < 8; ++k) s += hist[base + k];
        partial[tid] = s;
        __syncthreads();
        if (tid == 0) {
            int a = 0;
            for (int i = 0; i < 256; ++i) { int v = partial[i]; partial[i] = a; a += v; }
        }
        __syncthreads();
        int a = partial[tid];
        #pragma unroll
        for (int k = 0; k < 8; ++k) { int v = hist[base + k]; hist[base + k] = a; a += v; }
        __syncthreads();
        for (int n = tid; n < NN; n += 256) {
            int pos = atomicAdd(&hist[st[n]], 1);
            order[b * NN + pos] = n;
        }
    }
}

// ---- Span kernel: one wave per span (4 spans per 256-thread block).
//      No LDS, no __syncthreads. Single pass over span rows.
__global__ __launch_bounds__(256) void span_kernel(
    const float* __restrict__ emb,      // (B, S, H)
    const float* __restrict__ w,        // (H)  (fallback only)
    const float* __restrict__ bias,     // (1)  (fallback only)
    const int*   __restrict__ starts,   // (B, N)
    const int*   __restrict__ lengths,  // (B, N)
    const int*   __restrict__ order,    // (B, N) or nullptr
    const float* __restrict__ scores,   // (B*S) or nullptr
    float*       __restrict__ out)      // (B, N, 3H)
{
    const int tid  = threadIdx.x;
    const int wv   = tid >> 6;
    const int lane = tid & 63;
    const int bi   = blockIdx.x & 7;                 // example <-> XCD
    const int rank = ((int)blockIdx.x >> 3) * 4 + wv;
    const int n    = order ? order[bi * NN + rank] : rank;
    const int span = bi * NN + n;

    const int start = starts[span];
    const int len   = lengths[span];                 // valid t = 0..len, len <= 29

    const float* ebase = emb + (size_t)bi * SS * HH + (size_t)start * HH;
    const int h0 = lane * 4;

    // ---- per-lane score: lane t holds score of token t ----
    float sc;
    if (scores) {
        sc = (lane <= len) ? scores[bi * SS + start + lane] : -INFINITY;
    } else {
        // fallback (tiny ws): cooperative in-wave score pass
        float4 w0 = *reinterpret_cast<const float4*>(w + h0);
        float4 w1 = *reinterpret_cast<const float4*>(w + h0 + 256);
        float4 w2 = *reinterpret_cast<const float4*>(w + h0 + 512);
        sc = -INFINITY;
        for (int t = 0; t <= len; ++t) {
            const float* row = ebase + (size_t)t * HH;
            float4 v0 = *reinterpret_cast<const float4*>(row + h0);
            float4 v1 = *reinterpret_cast<const float4*>(row + h0 + 256);
            float4 v2 = *reinterpret_cast<const float4*>(row + h0 + 512);
            float d = v0.x * w0.x + v0.y * w0.y + v0.z * w0.z + v0.w * w0.w
                    + v1.x * w1.x + v1.y * w1.y + v1.z * w1.z + v1.w * w1.w
                    + v2.x * w2.x + v2.y * w2.y + v2.z * w2.z + v2.w * w2.w;
            #pragma unroll
            for (int off = 32; off; off >>= 1) d += __shfl_xor(d, off);
            if (lane == t) sc = d + bias[0];
        }
    }

    // ---- in-wave masked softmax ----
    float m = sc;
    #pragma unroll
    for (int off = 32; off; off >>= 1) m = fmaxf(m, __shfl_xor(m, off));
    float e = (lane <= len) ? __expf(sc - m) : 0.f;
    float sum = e;
    #pragma unroll
    for (int off = 32; off; off >>= 1) sum += __shfl_xor(sum, off);
    const float p = e / sum;

    // ---- single pass: weighted sum + start/end rows ----
    float* orow = out + (size_t)span * (3 * HH);
    float4 a0 = make_float4(0.f, 0.f, 0.f, 0.f);
    float4 a1 = a0, a2 = a0;
    const float* row = ebase;
    for (int t = 0; t <= len; ++t) {
        const float pt = __shfl(p, t);
        float4 v0 = *reinterpret_cast<const float4*>(row + h0);
        float4 v1 = *reinterpret_cast<const float4*>(row + h0 + 256);
        float4 v2 = *reinterpret_cast<const float4*>(row + h0 + 512);
        if (t == 0) {
            *reinterpret_cast<float4*>(orow + h0)       = v0;
            *reinterpret_cast<float4*>(orow + h0 + 256) = v1;
            *reinterpret_cast<float4*>(orow + h0 + 512) = v2;
        }
        if (t == len) {
            *reinterpret_cast<float4*>(orow + HH + h0)       = v0;
            *reinterpret_cast<float4*>(orow + HH + h0 + 256) = v1;
            *reinterpret_cast<float4*>(orow + HH + h0 + 512) = v2;
        }
        a0.x += pt * v0.x; a0.y += pt * v0.y; a0.z += pt * v0.z; a0.w += pt * v0.w;
        a1.x += pt * v1.x; a1.y += pt * v1.y; a1.z += pt * v1.z; a1.w += pt * v1.w;
        a2.x += pt * v2.x; a2.y += pt * v2.y; a2.z += pt * v2.z; a2.w += pt * v2.w;
        row += HH;
    }
    *reinterpret_cast<float4*>(orow + 2 * HH + h0)       = a0;
    *reinterpret_cast<float4*>(orow + 2 * HH + h0 + 256) = a1;
    *reinterpret_cast<float4*>(orow + 2 * HH + h0 + 512) = a2;
}

extern "C" void kernel_launch(void* const* d_in, const int* in_sizes, int n_in,
                              void* d_out, int out_size, void* d_ws, size_t ws_size,
                              hipStream_t stream) {
    const float* emb     = (const float*)d_in[0];
    const float* w       = (const float*)d_in[1];
    const float* bias    = (const float*)d_in[2];
    const int*   starts  = (const int*)d_in[3];
    const int*   lengths = (const int*)d_in[4];
    float*       out     = (float*)d_out;

    const size_t scores_bytes = (size_t)BB * SS * sizeof(float);
    const size_t order_bytes  = (size_t)BB * NN * sizeof(int);

    float* scores = nullptr;
    int*   order  = nullptr;
    if (ws_size >= scores_bytes + order_bytes) {
        scores = (float*)d_ws;
        order  = (int*)((char*)d_ws + scores_bytes);
    } else if (ws_size >= order_bytes) {
        order = (int*)d_ws;
    }

    if (scores || order) {
        const int gemv_blocks = scores ? GEMV_BLOCKS : 0;
        prep_kernel<<<dim3(gemv_blocks + BB), dim3(256), 0, stream>>>(
            emb, w, bias, starts, scores, order, gemv_blocks);
    }

    span_kernel<<<dim3(BB * NN / 4), dim3(256), 0, stream>>>(
        emb, w, bias, starts, lengths, order, scores, out);
}

// Round 4
// 31.789 us; speedup vs baseline: 1.1828x; 1.1828x over previous
//
#include <hip/hip_runtime.h>
#include <hip/hip_bf16.h>
#include <math.h>

#define BB 8
#define SS 2048
#define HH 768
#define NN 512
#define MAXW 30

// ---- Kernel A: per-example counting sort of spans by start (parallel scan) ----
__global__ __launch_bounds__(256) void sort_spans_kernel(
    const int* __restrict__ starts,   // (B, N)
    int*       __restrict__ order)    // (B, N): order[b*N + rank] = span idx
{
    const int b   = blockIdx.x;
    const int tid = threadIdx.x;
    __shared__ int hist[SS];
    __shared__ int wsum[4];

    for (int i = tid; i < SS; i += 256) hist[i] = 0;
    __syncthreads();

    const int* st = starts + b * NN;
    for (int n = tid; n < NN; n += 256) atomicAdd(&hist[st[n]], 1);
    __syncthreads();

    // each thread owns 8 bins; scan across 256 threads via shfl
    const int base = tid * 8;
    int cnt[8]; int s = 0;
    #pragma unroll
    for (int k = 0; k < 8; ++k) { cnt[k] = hist[base + k]; s += cnt[k]; }

    const int lane = tid & 63, wv = tid >> 6;
    int v = s;
    #pragma unroll
    for (int off = 1; off < 64; off <<= 1) {
        int u = __shfl_up(v, off);
        if (lane >= off) v += u;
    }
    if (lane == 63) wsum[wv] = v;
    __syncthreads();
    int wbase = 0;
    #pragma unroll
    for (int k = 0; k < 4; ++k) wbase += (k < wv) ? wsum[k] : 0;

    int excl = wbase + v - s;          // exclusive prefix of this thread's chunk
    #pragma unroll
    for (int k = 0; k < 8; ++k) { int c = cnt[k]; hist[base + k] = excl; excl += c; }
    __syncthreads();

    for (int n = tid; n < NN; n += 256) {
        int pos = atomicAdd(&hist[st[n]], 1);
        order[b * NN + pos] = n;
    }
}

// ---- Kernel B: fused single-pass span kernel. One wave per span,
//      online softmax (defer-rescale), 1-deep row prefetch.
//      No LDS, no __syncthreads.
__global__ __launch_bounds__(256) void span_fused_kernel(
    const float* __restrict__ emb,      // (B, S, H)
    const float* __restrict__ w,        // (H)
    const float* __restrict__ bias,     // (1)
    const int*   __restrict__ starts,   // (B, N)
    const int*   __restrict__ lengths,  // (B, N)
    const int*   __restrict__ order,    // (B, N) or nullptr
    float*       __restrict__ out)      // (B, N, 3H)
{
    const int tid  = threadIdx.x;
    const int wv   = tid >> 6;
    const int lane = tid & 63;
    const int bi   = blockIdx.x & 7;                 // example <-> XCD
    const int rank = ((int)blockIdx.x >> 3) * 4 + wv;
    const int n    = order ? order[bi * NN + rank] : rank;
    const int span = bi * NN + n;

    const int start = starts[span];
    const int len   = lengths[span];                 // valid t = 0..len (<= 29)

    const float* ebase = emb + (size_t)bi * SS * HH + (size_t)start * HH;
    const int h0 = lane * 4;
    float* orow = out + (size_t)span * (3 * HH);

    const float4 w0 = *reinterpret_cast<const float4*>(w + h0);
    const float4 w1 = *reinterpret_cast<const float4*>(w + h0 + 256);
    const float4 w2 = *reinterpret_cast<const float4*>(w + h0 + 512);
    const float bb = bias[0];

    // online softmax state (uniform across wave)
    float m = -INFINITY, ssum = 0.f;
    float4 a0 = make_float4(0.f, 0.f, 0.f, 0.f), a1 = a0, a2 = a0;

    // prefetch row 0
    const float* row = ebase;
    float4 v0 = *reinterpret_cast<const float4*>(row + h0);
    float4 v1 = *reinterpret_cast<const float4*>(row + h0 + 256);
    float4 v2 = *reinterpret_cast<const float4*>(row + h0 + 512);

    for (int t = 0; t <= len; ++t) {
        // prefetch next row while this one is processed
        float4 n0, n1, n2;
        if (t < len) {
            const float* nr = row + HH;
            n0 = *reinterpret_cast<const float4*>(nr + h0);
            n1 = *reinterpret_cast<const float4*>(nr + h0 + 256);
            n2 = *reinterpret_cast<const float4*>(nr + h0 + 512);
        }

        // dot(row, w) wave-reduced; all lanes end with the full sum
        float d = v0.x * w0.x + v0.y * w0.y + v0.z * w0.z + v0.w * w0.w
                + v1.x * w1.x + v1.y * w1.y + v1.z * w1.z + v1.w * w1.w
                + v2.x * w2.x + v2.y * w2.y + v2.z * w2.z + v2.w * w2.w;
        #pragma unroll
        for (int off = 32; off; off >>= 1) d += __shfl_xor(d, off);
        d += bb;

        // defer-rescale online softmax
        if (d > m) {                     // wave-uniform branch
            const float c = __expf(m - d);   // first iter: exp(-inf)=0
            ssum *= c;
            a0.x *= c; a0.y *= c; a0.z *= c; a0.w *= c;
            a1.x *= c; a1.y *= c; a1.z *= c; a1.w *= c;
            a2.x *= c; a2.y *= c; a2.z *= c; a2.w *= c;
            m = d;
        }
        const float pt = __expf(d - m);
        ssum += pt;
        a0.x += pt * v0.x; a0.y += pt * v0.y; a0.z += pt * v0.z; a0.w += pt * v0.w;
        a1.x += pt * v1.x; a1.y += pt * v1.y; a1.z += pt * v1.z; a1.w += pt * v1.w;
        a2.x += pt * v2.x; a2.y += pt * v2.y; a2.z += pt * v2.z; a2.w += pt * v2.w;

        if (t == 0) {                    // start row
            *reinterpret_cast<float4*>(orow + h0)       = v0;
            *reinterpret_cast<float4*>(orow + h0 + 256) = v1;
            *reinterpret_cast<float4*>(orow + h0 + 512) = v2;
        }
        if (t == len) {                  // end row
            *reinterpret_cast<float4*>(orow + HH + h0)       = v0;
            *reinterpret_cast<float4*>(orow + HH + h0 + 256) = v1;
            *reinterpret_cast<float4*>(orow + HH + h0 + 512) = v2;
        }

        v0 = n0; v1 = n1; v2 = n2;
        row += HH;
    }

    const float inv = 1.f / ssum;
    a0.x *= inv; a0.y *= inv; a0.z *= inv; a0.w *= inv;
    a1.x *= inv; a1.y *= inv; a1.z *= inv; a1.w *= inv;
    a2.x *= inv; a2.y *= inv; a2.z *= inv; a2.w *= inv;
    *reinterpret_cast<float4*>(orow + 2 * HH + h0)       = a0;
    *reinterpret_cast<float4*>(orow + 2 * HH + h0 + 256) = a1;
    *reinterpret_cast<float4*>(orow + 2 * HH + h0 + 512) = a2;
}

extern "C" void kernel_launch(void* const* d_in, const int* in_sizes, int n_in,
                              void* d_out, int out_size, void* d_ws, size_t ws_size,
                              hipStream_t stream) {
    const float* emb     = (const float*)d_in[0];
    const float* w       = (const float*)d_in[1];
    const float* bias    = (const float*)d_in[2];
    const int*   starts  = (const int*)d_in[3];
    const int*   lengths = (const int*)d_in[4];
    float*       out     = (float*)d_out;

    int* order = nullptr;
    if (ws_size >= (size_t)(BB * NN * sizeof(int))) {
        order = (int*)d_ws;
        sort_spans_kernel<<<dim3(BB), dim3(256), 0, stream>>>(starts, order);
    }

    span_fused_kernel<<<dim3(BB * NN / 4), dim3(256), 0, stream>>>(
        emb, w, bias, starts, lengths, order, out);
}